// Round 5
// baseline (166.923 us; speedup 1.0000x reference)
//
#include <hip/hip_runtime.h>

// B=4, C=256, HS=WS=64 -> N=4096 pixels/batch, 16384 total.
// NK=NV=32, NH=8, QKV = 1088, NH*QKV = 8704.
#define NPIX_TOTAL 16384
#define CDIM 256
#define NHEADS 8
#define QKVD 1088
#define NQKV 8704

typedef unsigned short u16;
typedef __attribute__((ext_vector_type(8))) __bf16 bf16x8;
typedef __attribute__((ext_vector_type(4))) float f32x4;
typedef __attribute__((ext_vector_type(2))) unsigned u32x2;

__device__ static inline u16 f2bf(float f) {
  union { float f; unsigned u; } x; x.f = f;
  unsigned r = x.u + 0x7fffu + ((x.u >> 16) & 1u);
  return (u16)(r >> 16);
}

__device__ static inline void gload_lds16(const void* g, void* l) {
  __builtin_amdgcn_global_load_lds((const __attribute__((address_space(1))) void*)g,
                                   (__attribute__((address_space(3))) void*)l,
                                   16, 0, 0);
}

// ---------------------------------------------------------------------------
__global__ __launch_bounds__(256) void transpose_cast(const float* __restrict__ x,
                                                      u16* __restrict__ xt) {
  __shared__ float t[64][65];
  const int b = blockIdx.z;
  const float* xb = x + (size_t)b * CDIM * 4096;
  u16* ob = xt + (size_t)b * 4096 * CDIM;
  const int n0 = blockIdx.x * 64;
  const int c0 = blockIdx.y * 64;
  const int tx = threadIdx.x & 63;
  const int ty = threadIdx.x >> 6;
#pragma unroll
  for (int i = 0; i < 16; ++i)
    t[ty + i * 4][tx] = xb[(size_t)(c0 + ty + i * 4) * 4096 + n0 + tx];
  __syncthreads();
#pragma unroll
  for (int i = 0; i < 16; ++i)
    ob[(size_t)(n0 + ty + i * 4) * CDIM + c0 + tx] = f2bf(t[tx][ty + i * 4]);
}

__global__ __launch_bounds__(256) void cast_bf(const float* __restrict__ in,
                                               u16* __restrict__ out, int n) {
  const int i = (blockIdx.x * 256 + threadIdx.x) * 4;
  if (i >= n) return;
  const f32x4 v = *(const f32x4*)(in + i);
  *(unsigned*)(out + i) = (unsigned)f2bf(v.x) | ((unsigned)f2bf(v.y) << 16);
  *(unsigned*)(out + i + 2) = (unsigned)f2bf(v.z) | ((unsigned)f2bf(v.w) << 16);
}

// ---------------------------------------------------------------------------
// Fused per-head qkv-GEMM + per-pixel attention, BARRIER-FREE main loop.
// Block = 128 pixels x 1 head, 512 threads = 8 waves (2 M-halves x 4 N-quarters).
// X-tile (128x256 bf16, 64KB) LDS-resident (XOR-swizzled); W streamed
// GLOBAL->REGISTER (L2-resident), double-buffered frags, no LDS, no barriers.
// Swapped-operand MFMA: D col(lane&15)=pixel, row((lane>>4)*4+j)=W-row.
// W K-row r => k = r>>5 (wave-uniform per frag-pair), v = r&31 (lane-local)
// -> qk[pix][v] += q[pix][k]*acc is a lane-local FMA with scalar q from LDS.
__global__ __launch_bounds__(512, 2) void fused_qkv_attn(const u16* __restrict__ Xbf,
                                                         const u16* __restrict__ Wbf,
                                                         u16* __restrict__ Abf) {
  __shared__ u16 A_lds[128 * 256];   // 64 KB; reused as f32 partials in epilogue
  __shared__ float q_lds[128 * 32];  // 16 KB, q[pix][k] chunk-swizzled

  const int tid = threadIdx.x;
  const int lane = tid & 63;
  const int l15 = lane & 15;
  const int hi = lane >> 4;
  const int wid = tid >> 6;   // 0..7
  const int wr = wid >> 2;    // M half
  const int wn = wid & 3;     // N quarter
  const int wm = wr * 64;

  const int head = blockIdx.x & 7;   // head pinned per XCD (heuristic)
  const int pixtile = blockIdx.x >> 3;
  const u16* Ag = Xbf + (size_t)pixtile * 128 * CDIM;
  const u16* Wh = Wbf + (size_t)head * QKVD * CDIM;

  // ---- A staging: global source pre-swizzled, LDS linear ----
#pragma unroll
  for (int i = 0; i < 8; ++i) {
    const int seg = wid * 8 + i;
    const int L = seg * 64 + lane;         // 16B chunk 0..4095
    const int row = L >> 5;                // 0..127
    const int c = L & 31;
    const int cs = (c & 24) | ((c & 7) ^ (row & 7));
    gload_lds16(Ag + (size_t)row * CDIM + cs * 8, (char*)A_lds + (size_t)seg * 1024);
  }

  // ---- qv-tile B frags: global->reg (q rows 0..31, v rows 1056..1087) ----
  const int brow = wn * 16 + l15;
  const u16* qvbase = Wh + (size_t)(brow < 32 ? brow : brow + 1024) * CDIM + hi * 8;
  bf16x8 bq[4][2];
#pragma unroll
  for (int kb = 0; kb < 4; ++kb)
#pragma unroll
    for (int kk2 = 0; kk2 < 2; ++kk2)
      bq[kb][kk2] = *(const bf16x8*)(qvbase + kb * 64 + kk2 * 32);

  __syncthreads();  // A_lds ready (implicit vmcnt0 drain covers gload_lds)

  auto afrag = [&](int mi, int kb, int kk2) -> bf16x8 {
    const int row = wm + mi * 16 + l15;
    const int ch = kb * 8 + ((kk2 * 4 + hi) ^ (row & 7));
    return *(const bf16x8*)(A_lds + row * 256 + ch * 8);
  };

  // ---- qv sub-GEMM: wave (wr,wn): 64 pix x 16 qv-cols ----
  f32x4 accq[4] = {};
#pragma unroll
  for (int kb = 0; kb < 4; ++kb)
#pragma unroll
    for (int kk2 = 0; kk2 < 2; ++kk2)
#pragma unroll
      for (int mi = 0; mi < 4; ++mi)
        accq[mi] = __builtin_amdgcn_mfma_f32_16x16x32_bf16(bq[kb][kk2], afrag(mi, kb, kk2),
                                                           accq[mi], 0, 0, 0);
  if (wn < 2) {  // stash q[pix][k] (k = wn*16+hi*4+j), chunk-swizzled
#pragma unroll
    for (int mi = 0; mi < 4; ++mi) {
      const int pix = wm + mi * 16 + l15;
      *(f32x4*)(q_lds + pix * 32 + ((wn * 4 + hi) ^ (pix & 7)) * 4) = accq[mi];
    }
  }
  __syncthreads();  // q visible to all waves

  // ---- main loop: 16 steps (4 N-subtiles x 4 BK), B global->reg dbuf ----
  f32x4 acc[4][4] = {};
  f32x4 qkr[4][2] = {};
  const u16* Bbase = Wh + (size_t)(32 + wn * 64 + l15) * CDIM + hi * 8;

  auto loadB = [&](bf16x8 (&dst)[2][4], int t) {
    const u16* p = Bbase + (size_t)(t >> 2) * 256 * CDIM + (t & 3) * 64;
#pragma unroll
    for (int kk2 = 0; kk2 < 2; ++kk2)
#pragma unroll
      for (int ni = 0; ni < 4; ++ni)
        dst[kk2][ni] = *(const bf16x8*)(p + (size_t)ni * 16 * CDIM + kk2 * 32);
  };

  auto mstep = [&](bf16x8 (&bfr)[2][4], int t) {
#pragma unroll
    for (int kk2 = 0; kk2 < 2; ++kk2) {
      bf16x8 af[4];
#pragma unroll
      for (int mi = 0; mi < 4; ++mi) af[mi] = afrag(mi, t & 3, kk2);
      __builtin_amdgcn_s_setprio(1);
#pragma unroll
      for (int mi = 0; mi < 4; ++mi)
#pragma unroll
        for (int ni = 0; ni < 4; ++ni)
          acc[mi][ni] = __builtin_amdgcn_mfma_f32_16x16x32_bf16(bfr[kk2][ni], af[mi],
                                                                acc[mi][ni], 0, 0, 0);
      __builtin_amdgcn_s_setprio(0);
    }
    if ((t & 3) == 3) {  // contraction: qk[pix][v] += q[pix][k]*K, lane-local
      const int s = t >> 2;
#pragma unroll
      for (int mi = 0; mi < 4; ++mi) {
        const int pix = wm + mi * 16 + l15;
        const float* qrow = q_lds + pix * 32;
#pragma unroll
        for (int kp = 0; kp < 2; ++kp) {
          const int k = s * 8 + wn * 2 + kp;
          const float qv_ = qrow[((k >> 2) ^ (pix & 7)) * 4 + (k & 3)];
          qkr[mi][0] += qv_ * acc[mi][kp * 2 + 0];
          qkr[mi][1] += qv_ * acc[mi][kp * 2 + 1];
        }
#pragma unroll
        for (int ni = 0; ni < 4; ++ni) acc[mi][ni] = (f32x4){0.f, 0.f, 0.f, 0.f};
      }
    }
  };

  bf16x8 bA[2][4], bB[2][4];
  loadB(bA, 0);
  loadB(bB, 1);
#pragma unroll
  for (int tt = 0; tt < 16; tt += 2) {
    mstep(bA, tt);
    if (tt + 2 < 16) loadB(bA, tt + 2);
    mstep(bB, tt + 1);
    if (tt + 3 < 16) loadB(bB, tt + 3);
  }

  // ---- epilogue: cross-wave k-reduction + softmax + a = p*v ----
  __syncthreads();                 // all waves done reading A_lds / q_lds
  float* part = (float*)A_lds;     // [wn 4][pix 128][v 32] f32 = 64 KB
#pragma unroll
  for (int mi = 0; mi < 4; ++mi)
#pragma unroll
    for (int par = 0; par < 2; ++par) {
      const int pix = wm + mi * 16 + l15;
      const int ch = (par * 4 + hi) ^ (pix & 7);
      *(f32x4*)(part + wn * 4096 + pix * 32 + ch * 4) = qkr[mi][par];
    }
  __syncthreads();

  const float scale = 0.17677669529663687f;  // 1/sqrt(32)
#pragma unroll
  for (int mi = 0; mi < 4; ++mi) {
    const int pix = wm + mi * 16 + l15;
    const int ch0 = hi ^ (pix & 7);
    const int ch1 = (4 + hi) ^ (pix & 7);
    f32x4 q0 = {0.f, 0.f, 0.f, 0.f}, q1 = {0.f, 0.f, 0.f, 0.f};
#pragma unroll
    for (int w = 0; w < 4; ++w) {
      q0 += *(const f32x4*)(part + w * 4096 + pix * 32 + ch0 * 4);
      q1 += *(const f32x4*)(part + w * 4096 + pix * 32 + ch1 * 4);
    }
    q0 *= scale; q1 *= scale;
    float m = fmaxf(fmaxf(fmaxf(q0.x, q0.y), fmaxf(q0.z, q0.w)),
                    fmaxf(fmaxf(q1.x, q1.y), fmaxf(q1.z, q1.w)));
    m = fmaxf(m, __shfl_xor(m, 16));
    m = fmaxf(m, __shfl_xor(m, 32));
    f32x4 e0, e1;
    e0.x = __expf(q0.x - m); e0.y = __expf(q0.y - m);
    e0.z = __expf(q0.z - m); e0.w = __expf(q0.w - m);
    e1.x = __expf(q1.x - m); e1.y = __expf(q1.y - m);
    e1.z = __expf(q1.z - m); e1.w = __expf(q1.w - m);
    float su = e0.x + e0.y + e0.z + e0.w + e1.x + e1.y + e1.z + e1.w;
    su += __shfl_xor(su, 16);
    su += __shfl_xor(su, 32);
    if (wn >= 2) {  // this wave holds v for par = wn-2; a = p*v
      const float inv = 1.0f / su;
      const f32x4 a = (wn == 2 ? e0 : e1) * (accq[mi] * inv);
      u32x2 p;
      p.x = (unsigned)f2bf(a.x) | ((unsigned)f2bf(a.y) << 16);
      p.y = (unsigned)f2bf(a.z) | ((unsigned)f2bf(a.w) << 16);
      const size_t gp = (size_t)(pixtile * 128 + pix) * 256 + head * 32 + (wn - 2) * 16 + hi * 4;
      *(u32x2*)(Abf + gp) = p;
    }
  }
}

// ---------------------------------------------------------------------------
// gemm2: out = a @ Wc^T + bc -> (B, C, 4096). 128x128, 2-phase dbuf, swizzled.
__global__ __launch_bounds__(256, 2) void gemm_out(const u16* __restrict__ A,
                                                   const u16* __restrict__ B,
                                                   float* __restrict__ Cout,
                                                   const float* __restrict__ bias) {
  __shared__ u16 As[2][128 * 64];
  __shared__ u16 Bs[2][128 * 64];
  const int tid = threadIdx.x;
  const int lane = tid & 63;
  const int wv = tid >> 6;
  const size_t m0 = (size_t)blockIdx.y * 128;
  const size_t n0 = (size_t)blockIdx.x * 128;
  const int wm = (wv >> 1) * 64;
  const int wn = (wv & 1) * 64;
  const int frow = lane & 15;
  const int fh = lane >> 4;
  const int fsw = frow & 7;

  f32x4 acc[4][4] = {};

  auto stage = [&](int buf, int kt) {
#pragma unroll
    for (int i = 0; i < 4; ++i) {
      const int L = (i * 4 + wv) * 64 + lane;
      const int r = L >> 3;
      const int cs = (L & 7) ^ (r & 7);
      const size_t goff = (size_t)r * CDIM + kt * 64 + cs * 8;
      gload_lds16(A + m0 * CDIM + goff, (char*)As[buf] + (size_t)(i * 4 + wv) * 1024);
      gload_lds16(B + n0 * CDIM + goff, (char*)Bs[buf] + (size_t)(i * 4 + wv) * 1024);
    }
  };

  stage(0, 0);
#pragma unroll
  for (int kt = 0; kt < 4; ++kt) {
    __syncthreads();
    if (kt < 3) stage((kt + 1) & 1, kt + 1);
    const u16* as = As[kt & 1];
    const u16* bs = Bs[kt & 1];
#pragma unroll
    for (int kk2 = 0; kk2 < 2; ++kk2) {
      const int kc = (kk2 * 4 + fh) ^ fsw;
      bf16x8 af[4], bfr[4];
#pragma unroll
      for (int mi = 0; mi < 4; ++mi)
        af[mi] = *(const bf16x8*)(as + (wm + mi * 16 + frow) * 64 + kc * 8);
#pragma unroll
      for (int ni = 0; ni < 4; ++ni)
        bfr[ni] = *(const bf16x8*)(bs + (wn + ni * 16 + frow) * 64 + kc * 8);
#pragma unroll
      for (int mi = 0; mi < 4; ++mi)
#pragma unroll
        for (int ni = 0; ni < 4; ++ni)
          acc[mi][ni] =
              __builtin_amdgcn_mfma_f32_16x16x32_bf16(af[mi], bfr[ni], acc[mi][ni], 0, 0, 0);
    }
  }

#pragma unroll
  for (int mi = 0; mi < 4; ++mi)
#pragma unroll
    for (int ni = 0; ni < 4; ++ni) {
      const size_t gm = m0 + wm + mi * 16 + fh * 4;
      const size_t gn = n0 + wn + ni * 16 + frow;
      f32x4 v = acc[mi][ni];
      v += bias[gn];
      const size_t b = gm >> 12;
      const size_t pix = gm & 4095;
      *(f32x4*)(Cout + ((b << 8) + gn) * 4096 + pix) = v;
    }
}

// ---------------------------------------------------------------------------
extern "C" void kernel_launch(void* const* d_in, const int* in_sizes, int n_in,
                              void* d_out, int out_size, void* d_ws, size_t ws_size,
                              hipStream_t stream) {
  (void)in_sizes; (void)n_in; (void)out_size; (void)ws_size;
  const float* x = (const float*)d_in[0];     // (4, 256, 64, 64)
  const float* Wqkv = (const float*)d_in[1];  // (8, 1088, 256)
  const float* Wc = (const float*)d_in[2];    // (256, 256)
  const float* bc = (const float*)d_in[3];    // (256,)
  float* out = (float*)d_out;                 // (4, 256, 64, 64)
  char* ws = (char*)d_ws;

  const size_t XBF_OFF = 0;               // 16384*256*2 = 8388608
  const size_t WBF_OFF = 8388608;         // 8704*256*2  = 4456448
  const size_t WCBF_OFF = 12845056;       // 256*256*2   = 131072
  const size_t ABF_OFF = 12976128;        // 16384*256*2 = 8388608
  u16* Xbf = (u16*)(ws + XBF_OFF);
  u16* Wbf = (u16*)(ws + WBF_OFF);
  u16* Wcbf = (u16*)(ws + WCBF_OFF);
  u16* Abf = (u16*)(ws + ABF_OFF);

  // stage 0: convert inputs to bf16
  transpose_cast<<<dim3(64, 4, 4), 256, 0, stream>>>(x, Xbf);
  cast_bf<<<(NQKV * CDIM) / 1024, 256, 0, stream>>>(Wqkv, Wbf, NQKV * CDIM);
  cast_bf<<<(CDIM * 256) / 1024, 256, 0, stream>>>(Wc, Wcbf, CDIM * 256);

  // stage 1: fused qkv-GEMM + attention (128 pixels x 1 head per block)
  fused_qkv_attn<<<dim3((NPIX_TOTAL / 128) * NHEADS), 512, 0, stream>>>(Xbf, Wbf, Abf);

  // stage 2: out = a @ Wc^T + bc -> (B, C, 4096)
  gemm_out<<<dim3(256 / 128, NPIX_TOTAL / 128), 256, 0, stream>>>(Abf, Wcbf, out, bc);
}

// Round 6
// 135.002 us; speedup vs baseline: 1.2365x; 1.2365x over previous
//
#include <hip/hip_runtime.h>

// B=4, C=256, HS=WS=64 -> N=4096 pixels/batch, 16384 total.
// NK=NV=32, NH=8, QKV = 1088, NH*QKV = 8704.
#define NPIX_TOTAL 16384
#define CDIM 256
#define NHEADS 8
#define QKVD 1088
#define NQKV 8704

typedef unsigned short u16;
typedef __attribute__((ext_vector_type(8))) __bf16 bf16x8;
typedef __attribute__((ext_vector_type(4))) float f32x4;
typedef __attribute__((ext_vector_type(2))) unsigned u32x2;

__device__ static inline u16 f2bf(float f) {
  union { float f; unsigned u; } x; x.f = f;
  unsigned r = x.u + 0x7fffu + ((x.u >> 16) & 1u);
  return (u16)(r >> 16);
}

__device__ static inline void gload_lds16(const void* g, void* l) {
  __builtin_amdgcn_global_load_lds((const __attribute__((address_space(1))) void*)g,
                                   (__attribute__((address_space(3))) void*)l,
                                   16, 0, 0);
}

#define WAITVM(N) asm volatile("s_waitcnt vmcnt(" #N ")" ::: "memory")
#define BARRIER() asm volatile("s_barrier" ::: "memory")

// ---------------------------------------------------------------------------
__global__ __launch_bounds__(256) void transpose_cast(const float* __restrict__ x,
                                                      u16* __restrict__ xt) {
  __shared__ float t[64][65];
  const int b = blockIdx.z;
  const float* xb = x + (size_t)b * CDIM * 4096;
  u16* ob = xt + (size_t)b * 4096 * CDIM;
  const int n0 = blockIdx.x * 64;
  const int c0 = blockIdx.y * 64;
  const int tx = threadIdx.x & 63;
  const int ty = threadIdx.x >> 6;
#pragma unroll
  for (int i = 0; i < 16; ++i)
    t[ty + i * 4][tx] = xb[(size_t)(c0 + ty + i * 4) * 4096 + n0 + tx];
  __syncthreads();
#pragma unroll
  for (int i = 0; i < 16; ++i)
    ob[(size_t)(n0 + ty + i * 4) * CDIM + c0 + tx] = f2bf(t[tx][ty + i * 4]);
}

__global__ __launch_bounds__(256) void cast_bf(const float* __restrict__ in,
                                               u16* __restrict__ out, int n) {
  const int i = (blockIdx.x * 256 + threadIdx.x) * 4;
  if (i >= n) return;
  const f32x4 v = *(const f32x4*)(in + i);
  *(unsigned*)(out + i) = (unsigned)f2bf(v.x) | ((unsigned)f2bf(v.y) << 16);
  *(unsigned*)(out + i + 2) = (unsigned)f2bf(v.z) | ((unsigned)f2bf(v.w) << 16);
}

// ---------------------------------------------------------------------------
// Fused per-head qkv-GEMM + per-pixel attention, depth-3 slab pipeline.
// Block = 128 pixels x 1 head, 512 threads = 8 waves (wr 2 x wn 4).
// A (X-tile 128x256, 64KB) LDS-resident; W K-part streams as 32 slabs of
// 128 rows x 64 k (16KB) through a 4-slot ring: one s_barrier + counted
// vmcnt(4) per step, 3 slabs in flight. A-frags cached in regs per kb
// (af LDS reads /4). Swapped-operand MFMA: col(lane&15)=pixel,
// row((lane>>4)*4+j)=W-row. Slab rows: k = sh*4+wn (uniform/wave),
// v = ni*16+hi*4+j (lane-local) -> per-step lane-local contraction
// qkr += q[pix][k]*acc (acc = kb-partial of K; contraction is linear).
__global__ __launch_bounds__(512, 2) void fused_qkv_attn(const u16* __restrict__ Xbf,
                                                         const u16* __restrict__ Wbf,
                                                         u16* __restrict__ Abf) {
  __shared__ u16 A_lds[128 * 256];    // 64 KB; f32 partials overlay in epilogue
  __shared__ u16 Bring[4][128 * 64];  // 64 KB ring; qv tile uses slots 0-1 in prologue
  __shared__ float q_lds[128 * 32];   // 16 KB, q[pix][k] chunk-swizzled

  const int tid = threadIdx.x;
  const int lane = tid & 63;
  const int l15 = lane & 15;
  const int hi = lane >> 4;
  const int wid = tid >> 6;   // 0..7
  const int wr = wid >> 2;    // pixel half
  const int wn = wid & 3;     // row quarter within 128-row slab
  const int wm = wr * 64;

  const int head = blockIdx.x & 7;   // head == XCD (round-robin dispatch)
  const int pixtile = blockIdx.x >> 3;
  const u16* Ag = Xbf + (size_t)pixtile * 128 * CDIM;
  const u16* Wh = Wbf + (size_t)head * QKVD * CDIM;

  // ---- prologue staging: A tile + qv tile (global pre-swizzled, LDS linear)
#pragma unroll
  for (int i = 0; i < 8; ++i) {
    const int seg = wid * 8 + i;
    const int L = seg * 64 + lane;         // 16B chunk 0..4095
    const int row = L >> 5;                // 0..127
    const int c = L & 31;
    const int cs = (c & 24) | ((c & 7) ^ (row & 7));
    gload_lds16(Ag + (size_t)row * CDIM + cs * 8, (char*)A_lds + (size_t)seg * 1024);
  }
#pragma unroll
  for (int i = 0; i < 4; ++i) {
    const int seg = wid * 4 + i;
    const int L = seg * 64 + lane;         // 0..2047
    const int row = L >> 5;                // 0..63
    const int c = L & 31;
    const int cs = (c & 24) | ((c & 7) ^ (row & 7));
    const int grow = row < 32 ? row : row + 1024;  // q rows 0..31, v rows 1056..1087
    gload_lds16(Wh + (size_t)grow * CDIM + cs * 8, (char*)&Bring[0][0] + (size_t)seg * 1024);
  }
  WAITVM(0);
  __syncthreads();

  auto afrag = [&](int mi, int kb, int kk2) -> bf16x8 {
    const int row = wm + mi * 16 + l15;
    const int ch = kb * 8 + ((kk2 * 4 + hi) ^ (row & 7));
    return *(const bf16x8*)(A_lds + row * 256 + ch * 8);
  };

  // ---- qv sub-GEMM: wave (wr,wn): 64 pix x 16 qv-cols ----
  f32x4 accq[4] = {};
  const int brow = wn * 16 + l15;
#pragma unroll
  for (int kb = 0; kb < 4; ++kb)
#pragma unroll
    for (int kk2 = 0; kk2 < 2; ++kk2) {
      const int bch = kb * 8 + ((kk2 * 4 + hi) ^ (brow & 7));
      const bf16x8 bq = *(const bf16x8*)(&Bring[0][0] + brow * 256 + bch * 8);
#pragma unroll
      for (int mi = 0; mi < 4; ++mi)
        accq[mi] = __builtin_amdgcn_mfma_f32_16x16x32_bf16(bq, afrag(mi, kb, kk2),
                                                           accq[mi], 0, 0, 0);
    }
  if (wn < 2) {  // stash q[pix][k] (k = wn*16+hi*4+j), chunk-swizzled
#pragma unroll
    for (int mi = 0; mi < 4; ++mi) {
      const int pix = wm + mi * 16 + l15;
      *(f32x4*)(q_lds + pix * 32 + ((wn * 4 + hi) ^ (pix & 7)) * 4) = accq[mi];
    }
  }
  __syncthreads();  // q visible; qv reads done -> ring free

  // ---- main loop: 32 slabs (kb = t>>3, sh = t&7), ring-4, depth-3 ----
  f32x4 acc[4][2] = {};
  f32x4 qkr[4][2] = {};
  bf16x8 afc[4][2];  // per-kb A-frag cache

  auto stage = [&](int t) {
    const int kb = t >> 3, sh = t & 7;
    u16* dst = &Bring[t & 3][0];
#pragma unroll
    for (int i = 0; i < 2; ++i) {
      const int L = i * 512 + wid * 64 + lane;   // chunk 0..1023
      const int row = L >> 3;                    // 0..127
      const int c8 = (L & 7) ^ (row & 7);
      gload_lds16(Wh + (size_t)(32 + sh * 128 + row) * CDIM + kb * 64 + c8 * 8,
                  (char*)dst + (size_t)(i * 512 + wid * 64) * 16);
    }
  };

  auto step = [&](int t) {
    const int sh = t & 7;
    if (sh == 0) {  // reload A-frag cache for this kb
      const int kb = t >> 3;
#pragma unroll
      for (int mi = 0; mi < 4; ++mi)
#pragma unroll
        for (int kk2 = 0; kk2 < 2; ++kk2) afc[mi][kk2] = afrag(mi, kb, kk2);
    }
    const u16* bs = &Bring[t & 3][0];
    bf16x8 bfr[2][2];
#pragma unroll
    for (int ni = 0; ni < 2; ++ni)
#pragma unroll
      for (int kk2 = 0; kk2 < 2; ++kk2) {
        const int rr = wn * 32 + ni * 16 + l15;
        bfr[ni][kk2] = *(const bf16x8*)(bs + rr * 64 + (((kk2 * 4 + hi) ^ (rr & 7))) * 8);
      }
    __builtin_amdgcn_s_setprio(1);
#pragma unroll
    for (int mi = 0; mi < 4; ++mi)
#pragma unroll
      for (int ni = 0; ni < 2; ++ni)
#pragma unroll
        for (int kk2 = 0; kk2 < 2; ++kk2)
          acc[mi][ni] = __builtin_amdgcn_mfma_f32_16x16x32_bf16(bfr[ni][kk2], afc[mi][kk2],
                                                                acc[mi][ni], 0, 0, 0);
    __builtin_amdgcn_s_setprio(0);
    // lane-local contraction with q (k = sh*4+wn uniform per wave)
#pragma unroll
    for (int mi = 0; mi < 4; ++mi) {
      const int pix = wm + mi * 16 + l15;
      const float qv_ = q_lds[pix * 32 + (sh ^ (pix & 7)) * 4 + wn];
      qkr[mi][0] += qv_ * acc[mi][0];
      qkr[mi][1] += qv_ * acc[mi][1];
      acc[mi][0] = (f32x4){0.f, 0.f, 0.f, 0.f};
      acc[mi][1] = (f32x4){0.f, 0.f, 0.f, 0.f};
    }
  };

  stage(0); stage(1); stage(2);   // 6 outstanding
#pragma unroll 1
  for (int t = 0; t < 30; ++t) {
    WAITVM(4);                    // slab t landed (retire oldest 2)
    BARRIER();                    // all waves: slab t ready, slab t-1 reads done
    if (t < 29) stage(t + 3);     // overwrite ring[(t-1)&3]
    step(t);
  }
  WAITVM(2); BARRIER(); step(30);
  WAITVM(0); BARRIER(); step(31);

  // ---- epilogue: cross-wave k-reduction + softmax + a = p*v ----
  __syncthreads();
  float* part = (float*)A_lds;  // [wn 4][pix 128][v 32] f32 = 64 KB
#pragma unroll
  for (int mi = 0; mi < 4; ++mi)
#pragma unroll
    for (int par = 0; par < 2; ++par) {
      const int pix = wm + mi * 16 + l15;
      const int ch = (par * 4 + hi) ^ (pix & 7);
      *(f32x4*)(part + wn * 4096 + pix * 32 + ch * 4) = qkr[mi][par];
    }
  __syncthreads();

  const float scale = 0.17677669529663687f;  // 1/sqrt(32)
#pragma unroll
  for (int mi = 0; mi < 4; ++mi) {
    const int pix = wm + mi * 16 + l15;
    const int ch0 = hi ^ (pix & 7);
    const int ch1 = (4 + hi) ^ (pix & 7);
    f32x4 q0 = {0.f, 0.f, 0.f, 0.f}, q1 = {0.f, 0.f, 0.f, 0.f};
#pragma unroll
    for (int w = 0; w < 4; ++w) {
      q0 += *(const f32x4*)(part + w * 4096 + pix * 32 + ch0 * 4);
      q1 += *(const f32x4*)(part + w * 4096 + pix * 32 + ch1 * 4);
    }
    q0 *= scale; q1 *= scale;
    float m = fmaxf(fmaxf(fmaxf(q0.x, q0.y), fmaxf(q0.z, q0.w)),
                    fmaxf(fmaxf(q1.x, q1.y), fmaxf(q1.z, q1.w)));
    m = fmaxf(m, __shfl_xor(m, 16));
    m = fmaxf(m, __shfl_xor(m, 32));
    f32x4 e0, e1;
    e0.x = __expf(q0.x - m); e0.y = __expf(q0.y - m);
    e0.z = __expf(q0.z - m); e0.w = __expf(q0.w - m);
    e1.x = __expf(q1.x - m); e1.y = __expf(q1.y - m);
    e1.z = __expf(q1.z - m); e1.w = __expf(q1.w - m);
    float su = e0.x + e0.y + e0.z + e0.w + e1.x + e1.y + e1.z + e1.w;
    su += __shfl_xor(su, 16);
    su += __shfl_xor(su, 32);
    if (wn >= 2) {  // this wave holds v for par = wn-2; a = p*v
      const float inv = 1.0f / su;
      const f32x4 a = (wn == 2 ? e0 : e1) * (accq[mi] * inv);
      u32x2 p;
      p.x = (unsigned)f2bf(a.x) | ((unsigned)f2bf(a.y) << 16);
      p.y = (unsigned)f2bf(a.z) | ((unsigned)f2bf(a.w) << 16);
      const size_t gp = (size_t)(pixtile * 128 + pix) * 256 + head * 32 + (wn - 2) * 16 + hi * 4;
      *(u32x2*)(Abf + gp) = p;
    }
  }
}

// ---------------------------------------------------------------------------
// gemm2: out = a @ Wc^T + bc -> (B, C, 4096). 128x128, 2-phase dbuf, swizzled.
__global__ __launch_bounds__(256, 2) void gemm_out(const u16* __restrict__ A,
                                                   const u16* __restrict__ B,
                                                   float* __restrict__ Cout,
                                                   const float* __restrict__ bias) {
  __shared__ u16 As[2][128 * 64];
  __shared__ u16 Bs[2][128 * 64];
  const int tid = threadIdx.x;
  const int lane = tid & 63;
  const int wv = tid >> 6;
  const size_t m0 = (size_t)blockIdx.y * 128;
  const size_t n0 = (size_t)blockIdx.x * 128;
  const int wm = (wv >> 1) * 64;
  const int wn = (wv & 1) * 64;
  const int frow = lane & 15;
  const int fh = lane >> 4;
  const int fsw = frow & 7;

  f32x4 acc[4][4] = {};

  auto stage = [&](int buf, int kt) {
#pragma unroll
    for (int i = 0; i < 4; ++i) {
      const int L = (i * 4 + wv) * 64 + lane;
      const int r = L >> 3;
      const int cs = (L & 7) ^ (r & 7);
      const size_t goff = (size_t)r * CDIM + kt * 64 + cs * 8;
      gload_lds16(A + m0 * CDIM + goff, (char*)As[buf] + (size_t)(i * 4 + wv) * 1024);
      gload_lds16(B + n0 * CDIM + goff, (char*)Bs[buf] + (size_t)(i * 4 + wv) * 1024);
    }
  };

  stage(0, 0);
#pragma unroll
  for (int kt = 0; kt < 4; ++kt) {
    __syncthreads();
    if (kt < 3) stage((kt + 1) & 1, kt + 1);
    const u16* as = As[kt & 1];
    const u16* bs = Bs[kt & 1];
#pragma unroll
    for (int kk2 = 0; kk2 < 2; ++kk2) {
      const int kc = (kk2 * 4 + fh) ^ fsw;
      bf16x8 af[4], bfr[4];
#pragma unroll
      for (int mi = 0; mi < 4; ++mi)
        af[mi] = *(const bf16x8*)(as + (wm + mi * 16 + frow) * 64 + kc * 8);
#pragma unroll
      for (int ni = 0; ni < 4; ++ni)
        bfr[ni] = *(const bf16x8*)(bs + (wn + ni * 16 + frow) * 64 + kc * 8);
#pragma unroll
      for (int mi = 0; mi < 4; ++mi)
#pragma unroll
        for (int ni = 0; ni < 4; ++ni)
          acc[mi][ni] =
              __builtin_amdgcn_mfma_f32_16x16x32_bf16(af[mi], bfr[ni], acc[mi][ni], 0, 0, 0);
    }
  }

#pragma unroll
  for (int mi = 0; mi < 4; ++mi)
#pragma unroll
    for (int ni = 0; ni < 4; ++ni) {
      const size_t gm = m0 + wm + mi * 16 + fh * 4;
      const size_t gn = n0 + wn + ni * 16 + frow;
      f32x4 v = acc[mi][ni];
      v += bias[gn];
      const size_t b = gm >> 12;
      const size_t pix = gm & 4095;
      *(f32x4*)(Cout + ((b << 8) + gn) * 4096 + pix) = v;
    }
}

// ---------------------------------------------------------------------------
extern "C" void kernel_launch(void* const* d_in, const int* in_sizes, int n_in,
                              void* d_out, int out_size, void* d_ws, size_t ws_size,
                              hipStream_t stream) {
  (void)in_sizes; (void)n_in; (void)out_size; (void)ws_size;
  const float* x = (const float*)d_in[0];     // (4, 256, 64, 64)
  const float* Wqkv = (const float*)d_in[1];  // (8, 1088, 256)
  const float* Wc = (const float*)d_in[2];    // (256, 256)
  const float* bc = (const float*)d_in[3];    // (256,)
  float* out = (float*)d_out;                 // (4, 256, 64, 64)
  char* ws = (char*)d_ws;

  const size_t XBF_OFF = 0;               // 16384*256*2 = 8388608
  const size_t WBF_OFF = 8388608;         // 8704*256*2  = 4456448
  const size_t WCBF_OFF = 12845056;       // 256*256*2   = 131072
  const size_t ABF_OFF = 12976128;        // 16384*256*2 = 8388608
  u16* Xbf = (u16*)(ws + XBF_OFF);
  u16* Wbf = (u16*)(ws + WBF_OFF);
  u16* Wcbf = (u16*)(ws + WCBF_OFF);
  u16* Abf = (u16*)(ws + ABF_OFF);

  // stage 0: convert inputs to bf16
  transpose_cast<<<dim3(64, 4, 4), 256, 0, stream>>>(x, Xbf);
  cast_bf<<<(NQKV * CDIM) / 1024, 256, 0, stream>>>(Wqkv, Wbf, NQKV * CDIM);
  cast_bf<<<(CDIM * 256) / 1024, 256, 0, stream>>>(Wc, Wcbf, CDIM * 256);

  // stage 1: fused qkv-GEMM + attention (128 pixels x 1 head per block)
  fused_qkv_attn<<<dim3((NPIX_TOTAL / 128) * NHEADS), 512, 0, stream>>>(Xbf, Wbf, Abf);

  // stage 2: out = a @ Wc^T + bc -> (B, C, 4096)
  gemm_out<<<dim3(256 / 128, NPIX_TOTAL / 128), 256, 0, stream>>>(Abf, Wcbf, out, bc);
}